// Round 6
// baseline (824.192 us; speedup 1.0000x reference)
//
#include <hip/hip_runtime.h>

#define D 128
#define NC 128            // edge chunks (= bucket_hist / bucket_scatter grid)
#define RPB 128           // rows per bucket
#define MAXBUCK 512

typedef short short8 __attribute__((ext_vector_type(8)));
typedef float v4f __attribute__((ext_vector_type(4)));

static __device__ __forceinline__ unsigned short f2bf(float f) {
    unsigned u = __builtin_bit_cast(unsigned, f);
    u = (u + 0x7FFFu + ((u >> 16) & 1u)) >> 16;   // RNE
    return (unsigned short)u;
}

// ---------------- prep: Wt[n][k] = (W||Wr)[k][n] as bf16 --------------------
__global__ __launch_bounds__(256) void prep(
    const float* __restrict__ W, const float* __restrict__ Wr,
    unsigned short* __restrict__ Wt)
{
    const int gid = blockIdx.x * 256 + threadIdx.x;
    if (gid < 2 * D * D) {
        const int k  = gid >> 8;
        const int nn = gid & 255;
        const float v = (nn < D) ? W[k * D + nn] : Wr[k * D + (nn - D)];
        Wt[nn * D + k] = f2bf(v);
    }
}

// ---------------- MFMA dual GEMM: support(bf16) = x@W, out(f32) = x@Wr ------
__global__ __launch_bounds__(256) void gemm_dual_mfma(
    const float* __restrict__ x, const unsigned short* __restrict__ Wt,
    unsigned short* __restrict__ support, float* __restrict__ out, int M)
{
    __shared__ unsigned short As[64][136];
    const int tid = threadIdx.x;
    const int w = tid >> 6;
    const int lane = tid & 63;
    const int nl = lane & 15, quad = lane >> 4;
    const int rowBase = blockIdx.x * 64;

    {
        const int r = tid & 63;
        const int seg = tid >> 6;
        const int row = rowBase + r;
        unsigned short tmp[32];
        if (row < M) {
            const float4* src = (const float4*)(x + (size_t)row * D + seg * 32);
            #pragma unroll
            for (int j = 0; j < 8; ++j) {
                const float4 v = src[j];
                tmp[j * 4 + 0] = f2bf(v.x); tmp[j * 4 + 1] = f2bf(v.y);
                tmp[j * 4 + 2] = f2bf(v.z); tmp[j * 4 + 3] = f2bf(v.w);
            }
        } else {
            #pragma unroll
            for (int j = 0; j < 32; ++j) tmp[j] = 0;
        }
        #pragma unroll
        for (int j = 0; j < 4; ++j)
            *(short8*)&As[r][seg * 32 + j * 8] = *(const short8*)&tmp[j * 8];
    }

    short8 bfrag[4][4];
    {
        const unsigned short* wbase = Wt + (size_t)(w * 64 + nl) * D + quad * 8;
        #pragma unroll
        for (int nt = 0; nt < 4; ++nt)
            #pragma unroll
            for (int c = 0; c < 4; ++c)
                bfrag[c][nt] = *(const short8*)(wbase + (size_t)nt * 16 * D + c * 32);
    }
    __syncthreads();

    v4f acc[4][4] = {};
    #pragma unroll
    for (int c = 0; c < 4; ++c) {
        short8 afr[4];
        #pragma unroll
        for (int mt = 0; mt < 4; ++mt)
            afr[mt] = *(const short8*)&As[mt * 16 + nl][c * 32 + quad * 8];
        #pragma unroll
        for (int mt = 0; mt < 4; ++mt)
            #pragma unroll
            for (int nt = 0; nt < 4; ++nt)
                acc[mt][nt] = __builtin_amdgcn_mfma_f32_16x16x32_bf16(
                    afr[mt], bfrag[c][nt], acc[mt][nt], 0, 0, 0);
    }

    const int cbase = (w & 1) * 64;
    if (w < 2) {
        #pragma unroll
        for (int mt = 0; mt < 4; ++mt)
            #pragma unroll
            for (int reg = 0; reg < 4; ++reg) {
                const int row = rowBase + mt * 16 + quad * 4 + reg;
                if (row < M) {
                    #pragma unroll
                    for (int nt = 0; nt < 4; ++nt)
                        support[(size_t)row * D + cbase + nt * 16 + nl] = f2bf(acc[mt][nt][reg]);
                }
            }
    } else {
        #pragma unroll
        for (int mt = 0; mt < 4; ++mt)
            #pragma unroll
            for (int reg = 0; reg < 4; ++reg) {
                const int row = rowBase + mt * 16 + quad * 4 + reg;
                if (row < M) {
                    #pragma unroll
                    for (int nt = 0; nt < 4; ++nt)
                        out[(size_t)row * D + cbase + nt * 16 + nl] = acc[mt][nt][reg];
                }
            }
    }
}

// ---------------- bucket histogram: countsT[b*NC + c] -----------------------
__global__ __launch_bounds__(256) void bucket_hist(
    const int* __restrict__ rows, int* __restrict__ countsT,
    int E, int nbuck, int chunk)
{
    __shared__ int hist[MAXBUCK];
    const int t = threadIdx.x, c = blockIdx.x;
    for (int i = t; i < nbuck; i += 256) hist[i] = 0;
    __syncthreads();
    const int base = c * chunk;
    const int endv = min(base + chunk, E);
    for (int e = base + t; e < endv; e += 256)
        atomicAdd(&hist[rows[e] >> 7], 1);
    __syncthreads();
    for (int i = t; i < nbuck; i += 256) countsT[i * NC + c] = hist[i];
}

// ---------------- scan trio (n = nbuck*NC) ----------------------------------
__global__ __launch_bounds__(256) void scan_local(
    const int* __restrict__ counts, int* __restrict__ eoff,
    int* __restrict__ block_sums, int n)
{
    __shared__ int tmp[256];
    const int b = blockIdx.x, t = threadIdx.x;
    const int base = b * 1024 + t * 4;
    int v0 = 0, v1 = 0, v2 = 0, v3 = 0;
    if (base + 3 < n) {
        const int4 q = *(const int4*)(counts + base);
        v0 = q.x; v1 = q.y; v2 = q.z; v3 = q.w;
    } else {
        if (base + 0 < n) v0 = counts[base + 0];
        if (base + 1 < n) v1 = counts[base + 1];
        if (base + 2 < n) v2 = counts[base + 2];
    }
    const int s01 = v0 + v1;
    const int tsum = s01 + v2 + v3;
    tmp[t] = tsum;
    __syncthreads();
    for (int off = 1; off < 256; off <<= 1) {
        const int u = (t >= off) ? tmp[t - off] : 0;
        __syncthreads();
        tmp[t] += u;
        __syncthreads();
    }
    const int excl = tmp[t] - tsum;
    const int e0 = excl, e1 = excl + v0, e2 = excl + s01, e3 = e2 + v2;
    if (base + 3 < n) {
        *(int4*)(eoff + base) = make_int4(e0, e1, e2, e3);
    } else {
        if (base + 0 < n) eoff[base + 0] = e0;
        if (base + 1 < n) eoff[base + 1] = e1;
        if (base + 2 < n) eoff[base + 2] = e2;
    }
    if (t == 255) block_sums[b] = tmp[255];
}

__global__ __launch_bounds__(64) void scan_blocks(
    int* __restrict__ block_sums, int* __restrict__ eoff, int nb, int n)
{
    __shared__ int tmp[64];
    const int t = threadIdx.x;
    const int v = (t < nb) ? block_sums[t] : 0;
    tmp[t] = v;
    __syncthreads();
    for (int off = 1; off < 64; off <<= 1) {
        const int u = (t >= off) ? tmp[t - off] : 0;
        __syncthreads();
        tmp[t] += u;
        __syncthreads();
    }
    if (t < nb) block_sums[t] = tmp[t] - v;
    if (t == 63) eoff[n] = tmp[63];   // == E
}

__global__ __launch_bounds__(256) void add_offsets(
    const int* __restrict__ block_sums, int* __restrict__ eoff, int n)
{
    const int b = blockIdx.x;
    const int off = block_sums[b];
    const int base = b * 1024 + threadIdx.x * 4;
    if (base + 3 < n) {
        int4 q = *(const int4*)(eoff + base);
        q.x += off; q.y += off; q.z += off; q.w += off;
        *(int4*)(eoff + base) = q;
    } else {
        #pragma unroll
        for (int j = 0; j < 4; ++j) {
            const int i = base + j;
            if (i < n) eoff[i] += off;
        }
    }
}

// ---------------- bucketed scatter: contiguous runs per (bucket,chunk) ------
__global__ __launch_bounds__(256) void bucket_scatter(
    const int* __restrict__ rows, const int* __restrict__ cols,
    const float* __restrict__ vals, const int* __restrict__ eoff,
    int2* __restrict__ sortedB, int E, int nbuck, int chunk)
{
    __shared__ int cur[MAXBUCK];
    const int t = threadIdx.x, c = blockIdx.x;
    for (int i = t; i < nbuck; i += 256) cur[i] = eoff[i * NC + c];
    __syncthreads();
    const int base = c * chunk;
    const int endv = min(base + chunk, E);
    for (int e = base + t; e < endv; e += 256) {
        const int r = rows[e];
        const int cl = cols[e];
        const float v = vals[e];
        const int b = r >> 7;
        const int pos = atomicAdd(&cur[b], 1);
        sortedB[pos] = make_int2(((r & (RPB - 1)) << 16) | cl, __float_as_int(v));
    }
}

// ---------------- bucket aggregate: LDS fp32 tile, batched gathers ----------
// acc layout de-interleaved: col 2L -> slot L, col 2L+1 -> slot 64+L
// so each lane's ds_add hits bank lane%32 (2-way, free).
__global__ __launch_bounds__(256) void bucket_agg(
    const int* __restrict__ eoff, const int2* __restrict__ sortedB,
    const unsigned short* __restrict__ support, float* __restrict__ out,
    int M, int E)
{
    __shared__ float acc[RPB * D];   // 64 KB
    const int t = threadIdx.x;
    const int b = blockIdx.x;
    {
        const float4 z = make_float4(0.f, 0.f, 0.f, 0.f);
        for (int i = t * 4; i < RPB * D; i += 1024) *(float4*)&acc[i] = z;
    }
    const int start = eoff[b * NC];
    const int endv  = eoff[(b + 1) * NC];
    __syncthreads();

    const int w = t >> 6, lane = t & 63;
    int i = start + w * 8;
    for (; i + 8 <= endv; i += 32) {
        const int4 q0 = *(const int4*)(sortedB + i + 0);
        const int4 q1 = *(const int4*)(sortedB + i + 2);
        const int4 q2 = *(const int4*)(sortedB + i + 4);
        const int4 q3 = *(const int4*)(sortedB + i + 6);
        const int hdr[8] = {q0.x, q0.z, q1.x, q1.z, q2.x, q2.z, q3.x, q3.z};
        const int vv[8]  = {q0.y, q0.w, q1.y, q1.w, q2.y, q2.w, q3.y, q3.w};
        unsigned p[8];
        #pragma unroll
        for (int j = 0; j < 8; ++j) {
            const int col = hdr[j] & 0xFFFF;
            p[j] = *(const unsigned*)(support + (size_t)col * D + lane * 2);
        }
        #pragma unroll
        for (int j = 0; j < 8; ++j) {
            const int rib = hdr[j] >> 16;
            const float v = __int_as_float(vv[j]);
            const float lo = __builtin_bit_cast(float, p[j] << 16) * v;
            const float hi = __builtin_bit_cast(float, p[j] & 0xFFFF0000u) * v;
            atomicAdd(&acc[rib * D + lane], lo);
            atomicAdd(&acc[rib * D + 64 + lane], hi);
        }
    }
    for (int j = 0; j < 8 && i + j < endv; ++j) {
        const int2 ed = sortedB[i + j];
        const int col = ed.x & 0xFFFF;
        const int rib = ed.x >> 16;
        const float v = __int_as_float(ed.y);
        const unsigned pj = *(const unsigned*)(support + (size_t)col * D + lane * 2);
        atomicAdd(&acc[rib * D + lane],      __builtin_bit_cast(float, pj << 16) * v);
        atomicAdd(&acc[rib * D + 64 + lane], __builtin_bit_cast(float, pj & 0xFFFF0000u) * v);
    }
    __syncthreads();

    // epilogue: out[row][4c..4c+3] += (acc[s=2c], acc[s=64+2c], acc[s=2c+1], acc[s=65+2c])
    for (int idx = t; idx < RPB * 32; idx += 256) {
        const int rib = idx >> 5;
        const int c = idx & 31;
        const int row = b * RPB + rib;
        if (row >= M) continue;
        const float2 lo2 = *(const float2*)&acc[rib * D + 2 * c];
        const float2 hi2 = *(const float2*)&acc[rib * D + 64 + 2 * c];
        float4* op = (float4*)(out + (size_t)row * D + 4 * c);
        float4 ov = *op;
        ov.x += lo2.x; ov.y += hi2.x; ov.z += lo2.y; ov.w += hi2.y;
        *op = ov;
    }
}

extern "C" void kernel_launch(void* const* d_in, const int* in_sizes, int n_in,
                              void* d_out, int out_size, void* d_ws, size_t ws_size,
                              hipStream_t stream) {
    const float* x     = (const float*)d_in[0];
    const int*   erows = (const int*)d_in[1];
    const int*   ecols = (const int*)d_in[2];
    const float* evals = (const float*)d_in[3];
    const float* W     = (const float*)d_in[4];
    const float* Wr    = (const float*)d_in[5];
    float* out = (float*)d_out;

    const int M = in_sizes[0] / D;   // 50000
    const int E = in_sizes[1];       // 800000

    const int nbuck = (M + RPB - 1) / RPB;         // 391
    const int n = nbuck * NC;                      // 50048
    const int chunk = (E + NC - 1) / NC;           // 6250

    // ws layout
    unsigned short* support = (unsigned short*)d_ws;            // M*D bf16
    unsigned short* Wt      = support + (size_t)M * D;          // 2*D*D bf16
    int*   countsT    = (int*)(Wt + 2 * D * D);                 // n
    int*   eoff       = countsT + n;                            // n+2
    int*   block_sums = eoff + n + 2;                           // 64
    int2*  sortedB    = (int2*)(block_sums + 64);               // E

    const int NB = (n + 1023) / 1024;              // 49

    prep<<<(2 * D * D + 255) / 256, 256, 0, stream>>>(W, Wr, Wt);
    gemm_dual_mfma<<<(M + 63) / 64, 256, 0, stream>>>(x, Wt, support, out, M);
    bucket_hist<<<NC, 256, 0, stream>>>(erows, countsT, E, nbuck, chunk);
    scan_local<<<NB, 256, 0, stream>>>(countsT, eoff, block_sums, n);
    scan_blocks<<<1, 64, 0, stream>>>(block_sums, eoff, NB, n);
    add_offsets<<<NB, 256, 0, stream>>>(block_sums, eoff, n);
    bucket_scatter<<<NC, 256, 0, stream>>>(erows, ecols, evals, eoff, sortedB, E, nbuck, chunk);
    bucket_agg<<<nbuck, 256, 0, stream>>>(eoff, sortedB, support, out, M, E);
}

// Round 7
// 221.697 us; speedup vs baseline: 3.7176x; 3.7176x over previous
//
#include <hip/hip_runtime.h>

#define D 128
#define NPART 8     // = XCD count; blockIdx%8 round-robins across XCDs
#define SUBC 64     // edge sub-chunks per partition

typedef short short8 __attribute__((ext_vector_type(8)));
typedef float v4f __attribute__((ext_vector_type(4)));

static __device__ __forceinline__ unsigned short f2bf(float f) {
    unsigned u = __builtin_bit_cast(unsigned, f);
    u = (u + 0x7FFFu + ((u >> 16) & 1u)) >> 16;   // RNE
    return (unsigned short)u;
}

// ---------------- prep: Wt[n][k] = (W||Wr)[k][n] as bf16; zero counts -------
__global__ __launch_bounds__(256) void prep(
    const float* __restrict__ W, const float* __restrict__ Wr,
    unsigned short* __restrict__ Wt, int* __restrict__ counts, int M)
{
    const int gid = blockIdx.x * 256 + threadIdx.x;
    if (gid < 2 * D * D) {
        const int k  = gid >> 8;
        const int nn = gid & 255;
        const float v = (nn < D) ? W[k * D + nn] : Wr[k * D + (nn - D)];
        Wt[nn * D + k] = f2bf(v);
    }
    if (gid < M) counts[gid] = 0;
}

// ---------------- MFMA dual GEMM: support(bf16) = x@W, out(f32) = x@Wr ------
__global__ __launch_bounds__(256) void gemm_dual_mfma(
    const float* __restrict__ x, const unsigned short* __restrict__ Wt,
    unsigned short* __restrict__ support, float* __restrict__ out, int M)
{
    __shared__ unsigned short As[64][136];
    const int tid = threadIdx.x;
    const int w = tid >> 6;
    const int lane = tid & 63;
    const int nl = lane & 15, quad = lane >> 4;
    const int rowBase = blockIdx.x * 64;

    {
        const int r = tid & 63;
        const int seg = tid >> 6;
        const int row = rowBase + r;
        unsigned short tmp[32];
        if (row < M) {
            const float4* src = (const float4*)(x + (size_t)row * D + seg * 32);
            #pragma unroll
            for (int j = 0; j < 8; ++j) {
                const float4 v = src[j];
                tmp[j * 4 + 0] = f2bf(v.x); tmp[j * 4 + 1] = f2bf(v.y);
                tmp[j * 4 + 2] = f2bf(v.z); tmp[j * 4 + 3] = f2bf(v.w);
            }
        } else {
            #pragma unroll
            for (int j = 0; j < 32; ++j) tmp[j] = 0;
        }
        #pragma unroll
        for (int j = 0; j < 4; ++j)
            *(short8*)&As[r][seg * 32 + j * 8] = *(const short8*)&tmp[j * 8];
    }

    short8 bfrag[4][4];
    {
        const unsigned short* wbase = Wt + (size_t)(w * 64 + nl) * D + quad * 8;
        #pragma unroll
        for (int nt = 0; nt < 4; ++nt)
            #pragma unroll
            for (int c = 0; c < 4; ++c)
                bfrag[c][nt] = *(const short8*)(wbase + (size_t)nt * 16 * D + c * 32);
    }
    __syncthreads();

    v4f acc[4][4] = {};
    #pragma unroll
    for (int c = 0; c < 4; ++c) {
        short8 afr[4];
        #pragma unroll
        for (int mt = 0; mt < 4; ++mt)
            afr[mt] = *(const short8*)&As[mt * 16 + nl][c * 32 + quad * 8];
        #pragma unroll
        for (int mt = 0; mt < 4; ++mt)
            #pragma unroll
            for (int nt = 0; nt < 4; ++nt)
                acc[mt][nt] = __builtin_amdgcn_mfma_f32_16x16x32_bf16(
                    afr[mt], bfrag[c][nt], acc[mt][nt], 0, 0, 0);
    }

    const int cbase = (w & 1) * 64;
    if (w < 2) {
        #pragma unroll
        for (int mt = 0; mt < 4; ++mt)
            #pragma unroll
            for (int reg = 0; reg < 4; ++reg) {
                const int row = rowBase + mt * 16 + quad * 4 + reg;
                if (row < M) {
                    #pragma unroll
                    for (int nt = 0; nt < 4; ++nt)
                        support[(size_t)row * D + cbase + nt * 16 + nl] = f2bf(acc[mt][nt][reg]);
                }
            }
    } else {
        #pragma unroll
        for (int mt = 0; mt < 4; ++mt)
            #pragma unroll
            for (int reg = 0; reg < 4; ++reg) {
                const int row = rowBase + mt * 16 + quad * 4 + reg;
                if (row < M) {
                    #pragma unroll
                    for (int nt = 0; nt < 4; ++nt)
                        out[(size_t)row * D + cbase + nt * 16 + nl] = acc[mt][nt][reg];
                }
            }
    }
}

// ---------------- CSR build ------------------------------------------------
__global__ __launch_bounds__(256) void edge_histogram(
    const int* __restrict__ rows, int* __restrict__ counts, int E)
{
    const int e = blockIdx.x * 256 + threadIdx.x;
    if (e < E) atomicAdd(&counts[rows[e]], 1);
}

__global__ __launch_bounds__(256) void scan_local(
    const int* __restrict__ counts, int* __restrict__ row_start,
    int* __restrict__ block_sums, int n)
{
    __shared__ int tmp[256];
    const int b = blockIdx.x, t = threadIdx.x;
    const int base = b * 1024 + t * 4;
    int v0 = 0, v1 = 0, v2 = 0, v3 = 0;
    if (base + 3 < n) {
        const int4 q = *(const int4*)(counts + base);
        v0 = q.x; v1 = q.y; v2 = q.z; v3 = q.w;
    } else {
        if (base + 0 < n) v0 = counts[base + 0];
        if (base + 1 < n) v1 = counts[base + 1];
        if (base + 2 < n) v2 = counts[base + 2];
    }
    const int s01 = v0 + v1;
    const int tsum = s01 + v2 + v3;
    tmp[t] = tsum;
    __syncthreads();
    for (int off = 1; off < 256; off <<= 1) {
        const int u = (t >= off) ? tmp[t - off] : 0;
        __syncthreads();
        tmp[t] += u;
        __syncthreads();
    }
    const int excl = tmp[t] - tsum;
    const int e0 = excl, e1 = excl + v0, e2 = excl + s01, e3 = e2 + v2;
    if (base + 3 < n) {
        *(int4*)(row_start + base) = make_int4(e0, e1, e2, e3);
    } else {
        if (base + 0 < n) row_start[base + 0] = e0;
        if (base + 1 < n) row_start[base + 1] = e1;
        if (base + 2 < n) row_start[base + 2] = e2;
    }
    if (t == 255) block_sums[b] = tmp[255];
}

__global__ __launch_bounds__(64) void scan_blocks(
    int* __restrict__ block_sums, int* __restrict__ row_start, int nb, int n)
{
    __shared__ int tmp[64];
    const int t = threadIdx.x;
    const int v = (t < nb) ? block_sums[t] : 0;
    tmp[t] = v;
    __syncthreads();
    for (int off = 1; off < 64; off <<= 1) {
        const int u = (t >= off) ? tmp[t - off] : 0;
        __syncthreads();
        tmp[t] += u;
        __syncthreads();
    }
    if (t < nb) block_sums[t] = tmp[t] - v;
    if (t == 63) row_start[n] = tmp[63];
}

__global__ __launch_bounds__(256) void add_offsets(
    const int* __restrict__ block_sums, int* __restrict__ row_start,
    int* __restrict__ cursor, int n)
{
    const int b = blockIdx.x;
    const int off = block_sums[b];
    const int base = b * 1024 + threadIdx.x * 4;
    if (base + 3 < n) {
        int4 q = *(const int4*)(row_start + base);
        q.x += off; q.y += off; q.z += off; q.w += off;
        *(int4*)(row_start + base) = q;
        *(int4*)(cursor + base) = q;
    } else {
        #pragma unroll
        for (int j = 0; j < 4; ++j) {
            const int i = base + j;
            if (i < n) {
                const int v = row_start[i] + off;
                row_start[i] = v;
                cursor[i] = v;
            }
        }
    }
}

// ---------------- XCD-partitioned scatter ----------------------------------
// Partition p owns rows [p*rpp, (p+1)*rpp) whose CSR slots are one contiguous
// region of `sorted`. blockIdx%8 keeps each region's writers on one XCD so
// its private L2 merges the 8B stores into full-line writebacks.
__global__ __launch_bounds__(256) void part_scatter(
    const int* __restrict__ rows, const int* __restrict__ cols,
    const float* __restrict__ vals, int* __restrict__ cursor,
    int2* __restrict__ sorted, int E, int rpp)
{
    const int part = blockIdx.x & (NPART - 1);
    const int sub  = blockIdx.x >> 3;
    const int chunk = (E + SUBC - 1) / SUBC;
    const int base = sub * chunk;
    const int endv = min(base + chunk, E);
    const int lo = part * rpp;
    const int hi = lo + rpp;
    for (int e = base + threadIdx.x; e < endv; e += 256) {
        const int r = rows[e];
        if (r >= lo && r < hi) {
            const int pos = atomicAdd(&cursor[r], 1);
            sorted[pos] = make_int2(cols[e], __float_as_int(vals[e]));
        }
    }
}

// ---------------- Aggregation: wave per row, batched independent gathers ----
__global__ __launch_bounds__(256) void row_aggregate(
    const int* __restrict__ row_start, const int2* __restrict__ sorted,
    const unsigned short* __restrict__ support, float* __restrict__ out, int N)
{
    const int row = blockIdx.x * 4 + (threadIdx.x >> 6);
    const int lane = threadIdx.x & 63;
    if (row >= N) return;
    const int s = row_start[row];
    const int e = row_start[row + 1];
    if (s == e) return;

    float ax = 0.f, ay = 0.f;
    int i = s;

    for (; i + 8 <= e; i += 8) {
        int4 q0 = *(const int4*)(sorted + i + 0);
        int4 q1 = *(const int4*)(sorted + i + 2);
        int4 q2 = *(const int4*)(sorted + i + 4);
        int4 q3 = *(const int4*)(sorted + i + 6);
        const int  c[8] = {q0.x, q0.z, q1.x, q1.z, q2.x, q2.z, q3.x, q3.z};
        const int  vv[8] = {q0.y, q0.w, q1.y, q1.w, q2.y, q2.w, q3.y, q3.w};
        unsigned p[8];
        #pragma unroll
        for (int j = 0; j < 8; ++j)
            p[j] = *(const unsigned*)(support + (size_t)c[j] * D + lane * 2);
        #pragma unroll
        for (int j = 0; j < 8; ++j) {
            const float v = __int_as_float(vv[j]);
            ax += __builtin_bit_cast(float, p[j] << 16) * v;
            ay += __builtin_bit_cast(float, p[j] & 0xFFFF0000u) * v;
        }
    }

    if (i < e) {
        const int m = e - i;   // 1..7
        int cc[8]; float vv[8];
        #pragma unroll
        for (int j = 0; j < 8; ++j) {
            const int idx = i + (j < m ? j : m - 1);
            const int2 ed = sorted[idx];
            cc[j] = ed.x;
            vv[j] = (j < m) ? __int_as_float(ed.y) : 0.f;
        }
        unsigned p[8];
        #pragma unroll
        for (int j = 0; j < 8; ++j)
            p[j] = *(const unsigned*)(support + (size_t)cc[j] * D + lane * 2);
        #pragma unroll
        for (int j = 0; j < 8; ++j) {
            ax += __builtin_bit_cast(float, p[j] << 16) * vv[j];
            ay += __builtin_bit_cast(float, p[j] & 0xFFFF0000u) * vv[j];
        }
    }

    float* o = out + (size_t)row * D + lane * 2;
    float2 ov = *(const float2*)o;
    ov.x += ax;
    ov.y += ay;
    *(float2*)o = ov;
}

extern "C" void kernel_launch(void* const* d_in, const int* in_sizes, int n_in,
                              void* d_out, int out_size, void* d_ws, size_t ws_size,
                              hipStream_t stream) {
    const float* x     = (const float*)d_in[0];
    const int*   erows = (const int*)d_in[1];
    const int*   ecols = (const int*)d_in[2];
    const float* evals = (const float*)d_in[3];
    const float* W     = (const float*)d_in[4];
    const float* Wr    = (const float*)d_in[5];
    float* out = (float*)d_out;

    const int M = in_sizes[0] / D;   // 50000
    const int E = in_sizes[1];       // 800000

    unsigned short* support = (unsigned short*)d_ws;            // M*D bf16
    unsigned short* Wt      = support + (size_t)M * D;          // 2*D*D bf16
    int*   counts     = (int*)(Wt + 2 * D * D);                 // M
    int*   row_start  = counts + M;                             // M+2
    int*   cursor     = row_start + M + 2;                      // M
    int*   block_sums = cursor + M;                             // 64
    int2*  sorted     = (int2*)(block_sums + 64);               // E

    const int NB = (M + 1023) / 1024;           // 49
    const int eb = (E + 255) / 256;
    const int prep_grid = ((M > 2 * D * D ? M : 2 * D * D) + 255) / 256;
    const int rpp = (M + NPART - 1) / NPART;    // 6250 rows per partition

    prep<<<prep_grid, 256, 0, stream>>>(W, Wr, Wt, counts, M);
    gemm_dual_mfma<<<(M + 63) / 64, 256, 0, stream>>>(x, Wt, support, out, M);
    edge_histogram<<<eb, 256, 0, stream>>>(erows, counts, E);
    scan_local<<<NB, 256, 0, stream>>>(counts, row_start, block_sums, M);
    scan_blocks<<<1, 64, 0, stream>>>(block_sums, row_start, NB, M);
    add_offsets<<<NB, 256, 0, stream>>>(block_sums, row_start, cursor, M);
    part_scatter<<<NPART * SUBC, 256, 0, stream>>>(erows, ecols, evals, cursor, sorted, E, rpp);
    row_aggregate<<<(M + 3) / 4, 256, 0, stream>>>(row_start, sorted, support, out, M);
}

// Round 8
// 220.845 us; speedup vs baseline: 3.7320x; 1.0039x over previous
//
#include <hip/hip_runtime.h>

#define D 128
#define NPART 8     // = XCD count; blockIdx%8 round-robins across XCDs
#define SUBC 256    // edge sub-chunks per partition (2048 blocks total)

typedef short short8 __attribute__((ext_vector_type(8)));
typedef float v4f __attribute__((ext_vector_type(4)));

static __device__ __forceinline__ unsigned short f2bf(float f) {
    unsigned u = __builtin_bit_cast(unsigned, f);
    u = (u + 0x7FFFu + ((u >> 16) & 1u)) >> 16;   // RNE
    return (unsigned short)u;
}

// ---------------- prep: Wt[n][k] = (W||Wr)[k][n] as bf16; zero counts -------
__global__ __launch_bounds__(256) void prep(
    const float* __restrict__ W, const float* __restrict__ Wr,
    unsigned short* __restrict__ Wt, int* __restrict__ counts, int M)
{
    const int gid = blockIdx.x * 256 + threadIdx.x;
    if (gid < 2 * D * D) {
        const int k  = gid >> 8;
        const int nn = gid & 255;
        const float v = (nn < D) ? W[k * D + nn] : Wr[k * D + (nn - D)];
        Wt[nn * D + k] = f2bf(v);
    }
    if (gid < M) counts[gid] = 0;
}

// ---------------- MFMA dual GEMM: support(bf16) = x@W, out(f32) = x@Wr ------
__global__ __launch_bounds__(256) void gemm_dual_mfma(
    const float* __restrict__ x, const unsigned short* __restrict__ Wt,
    unsigned short* __restrict__ support, float* __restrict__ out, int M)
{
    __shared__ unsigned short As[64][136];
    const int tid = threadIdx.x;
    const int w = tid >> 6;
    const int lane = tid & 63;
    const int nl = lane & 15, quad = lane >> 4;
    const int rowBase = blockIdx.x * 64;

    {
        const int r = tid & 63;
        const int seg = tid >> 6;
        const int row = rowBase + r;
        unsigned short tmp[32];
        if (row < M) {
            const float4* src = (const float4*)(x + (size_t)row * D + seg * 32);
            #pragma unroll
            for (int j = 0; j < 8; ++j) {
                const float4 v = src[j];
                tmp[j * 4 + 0] = f2bf(v.x); tmp[j * 4 + 1] = f2bf(v.y);
                tmp[j * 4 + 2] = f2bf(v.z); tmp[j * 4 + 3] = f2bf(v.w);
            }
        } else {
            #pragma unroll
            for (int j = 0; j < 32; ++j) tmp[j] = 0;
        }
        #pragma unroll
        for (int j = 0; j < 4; ++j)
            *(short8*)&As[r][seg * 32 + j * 8] = *(const short8*)&tmp[j * 8];
    }

    short8 bfrag[4][4];
    {
        const unsigned short* wbase = Wt + (size_t)(w * 64 + nl) * D + quad * 8;
        #pragma unroll
        for (int nt = 0; nt < 4; ++nt)
            #pragma unroll
            for (int c = 0; c < 4; ++c)
                bfrag[c][nt] = *(const short8*)(wbase + (size_t)nt * 16 * D + c * 32);
    }
    __syncthreads();

    v4f acc[4][4] = {};
    #pragma unroll
    for (int c = 0; c < 4; ++c) {
        short8 afr[4];
        #pragma unroll
        for (int mt = 0; mt < 4; ++mt)
            afr[mt] = *(const short8*)&As[mt * 16 + nl][c * 32 + quad * 8];
        #pragma unroll
        for (int mt = 0; mt < 4; ++mt)
            #pragma unroll
            for (int nt = 0; nt < 4; ++nt)
                acc[mt][nt] = __builtin_amdgcn_mfma_f32_16x16x32_bf16(
                    afr[mt], bfrag[c][nt], acc[mt][nt], 0, 0, 0);
    }

    const int cbase = (w & 1) * 64;
    if (w < 2) {
        #pragma unroll
        for (int mt = 0; mt < 4; ++mt)
            #pragma unroll
            for (int reg = 0; reg < 4; ++reg) {
                const int row = rowBase + mt * 16 + quad * 4 + reg;
                if (row < M) {
                    #pragma unroll
                    for (int nt = 0; nt < 4; ++nt)
                        support[(size_t)row * D + cbase + nt * 16 + nl] = f2bf(acc[mt][nt][reg]);
                }
            }
    } else {
        #pragma unroll
        for (int mt = 0; mt < 4; ++mt)
            #pragma unroll
            for (int reg = 0; reg < 4; ++reg) {
                const int row = rowBase + mt * 16 + quad * 4 + reg;
                if (row < M) {
                    #pragma unroll
                    for (int nt = 0; nt < 4; ++nt)
                        out[(size_t)row * D + cbase + nt * 16 + nl] = acc[mt][nt][reg];
                }
            }
    }
}

// ---------------- CSR build ------------------------------------------------
__global__ __launch_bounds__(256) void edge_histogram(
    const int* __restrict__ rows, int* __restrict__ counts, int E)
{
    const int e = blockIdx.x * 256 + threadIdx.x;
    if (e < E) atomicAdd(&counts[__builtin_nontemporal_load(rows + e)], 1);
}

__global__ __launch_bounds__(256) void scan_local(
    const int* __restrict__ counts, int* __restrict__ row_start,
    int* __restrict__ block_sums, int n)
{
    __shared__ int tmp[256];
    const int b = blockIdx.x, t = threadIdx.x;
    const int base = b * 1024 + t * 4;
    int v0 = 0, v1 = 0, v2 = 0, v3 = 0;
    if (base + 3 < n) {
        const int4 q = *(const int4*)(counts + base);
        v0 = q.x; v1 = q.y; v2 = q.z; v3 = q.w;
    } else {
        if (base + 0 < n) v0 = counts[base + 0];
        if (base + 1 < n) v1 = counts[base + 1];
        if (base + 2 < n) v2 = counts[base + 2];
    }
    const int s01 = v0 + v1;
    const int tsum = s01 + v2 + v3;
    tmp[t] = tsum;
    __syncthreads();
    for (int off = 1; off < 256; off <<= 1) {
        const int u = (t >= off) ? tmp[t - off] : 0;
        __syncthreads();
        tmp[t] += u;
        __syncthreads();
    }
    const int excl = tmp[t] - tsum;
    const int e0 = excl, e1 = excl + v0, e2 = excl + s01, e3 = e2 + v2;
    if (base + 3 < n) {
        *(int4*)(row_start + base) = make_int4(e0, e1, e2, e3);
    } else {
        if (base + 0 < n) row_start[base + 0] = e0;
        if (base + 1 < n) row_start[base + 1] = e1;
        if (base + 2 < n) row_start[base + 2] = e2;
    }
    if (t == 255) block_sums[b] = tmp[255];
}

__global__ __launch_bounds__(64) void scan_blocks(
    int* __restrict__ block_sums, int* __restrict__ row_start, int nb, int n)
{
    __shared__ int tmp[64];
    const int t = threadIdx.x;
    const int v = (t < nb) ? block_sums[t] : 0;
    tmp[t] = v;
    __syncthreads();
    for (int off = 1; off < 64; off <<= 1) {
        const int u = (t >= off) ? tmp[t - off] : 0;
        __syncthreads();
        tmp[t] += u;
        __syncthreads();
    }
    if (t < nb) block_sums[t] = tmp[t] - v;
    if (t == 63) row_start[n] = tmp[63];
}

__global__ __launch_bounds__(256) void add_offsets(
    const int* __restrict__ block_sums, int* __restrict__ row_start,
    int* __restrict__ cursor, int n)
{
    const int b = blockIdx.x;
    const int off = block_sums[b];
    const int base = b * 1024 + threadIdx.x * 4;
    if (base + 3 < n) {
        int4 q = *(const int4*)(row_start + base);
        q.x += off; q.y += off; q.z += off; q.w += off;
        *(int4*)(row_start + base) = q;
        *(int4*)(cursor + base) = q;
    } else {
        #pragma unroll
        for (int j = 0; j < 4; ++j) {
            const int i = base + j;
            if (i < n) {
                const int v = row_start[i] + off;
                row_start[i] = v;
                cursor[i] = v;
            }
        }
    }
}

// ---------------- XCD-partitioned scatter ----------------------------------
// Partition p owns rows [p*rpp, (p+1)*rpp): one contiguous ~800KB region of
// `sorted`, written only by blocks on XCD p (blockIdx%8). Edge-array reads are
// single-use per XCD -> non-temporal, so they don't evict the write-merge
// lines from that XCD's L2.
__global__ __launch_bounds__(256) void part_scatter(
    const int* __restrict__ rows, const int* __restrict__ cols,
    const float* __restrict__ vals, int* __restrict__ cursor,
    int2* __restrict__ sorted, int E, int rpp)
{
    const int part = blockIdx.x & (NPART - 1);
    const int sub  = blockIdx.x >> 3;
    const int chunk = (E + SUBC - 1) / SUBC;
    const int base = sub * chunk;
    const int endv = min(base + chunk, E);
    const int lo = part * rpp;
    const int hi = lo + rpp;
    for (int e = base + threadIdx.x; e < endv; e += 256) {
        const int r = __builtin_nontemporal_load(rows + e);
        if (r >= lo && r < hi) {
            const int   cl = __builtin_nontemporal_load(cols + e);
            const float v  = __builtin_nontemporal_load(vals + e);
            const int pos = atomicAdd(&cursor[r], 1);
            sorted[pos] = make_int2(cl, __float_as_int(v));
        }
    }
}

// ---------------- Aggregation: wave per row, batched independent gathers ----
__global__ __launch_bounds__(256) void row_aggregate(
    const int* __restrict__ row_start, const int2* __restrict__ sorted,
    const unsigned short* __restrict__ support, float* __restrict__ out, int N)
{
    const int row = blockIdx.x * 4 + (threadIdx.x >> 6);
    const int lane = threadIdx.x & 63;
    if (row >= N) return;
    const int s = row_start[row];
    const int e = row_start[row + 1];
    if (s == e) return;

    float ax = 0.f, ay = 0.f;
    int i = s;

    for (; i + 8 <= e; i += 8) {
        int4 q0 = *(const int4*)(sorted + i + 0);
        int4 q1 = *(const int4*)(sorted + i + 2);
        int4 q2 = *(const int4*)(sorted + i + 4);
        int4 q3 = *(const int4*)(sorted + i + 6);
        const int  c[8] = {q0.x, q0.z, q1.x, q1.z, q2.x, q2.z, q3.x, q3.z};
        const int  vv[8] = {q0.y, q0.w, q1.y, q1.w, q2.y, q2.w, q3.y, q3.w};
        unsigned p[8];
        #pragma unroll
        for (int j = 0; j < 8; ++j)
            p[j] = *(const unsigned*)(support + (size_t)c[j] * D + lane * 2);
        #pragma unroll
        for (int j = 0; j < 8; ++j) {
            const float v = __int_as_float(vv[j]);
            ax += __builtin_bit_cast(float, p[j] << 16) * v;
            ay += __builtin_bit_cast(float, p[j] & 0xFFFF0000u) * v;
        }
    }

    if (i < e) {
        const int m = e - i;   // 1..7
        int cc[8]; float vv[8];
        #pragma unroll
        for (int j = 0; j < 8; ++j) {
            const int idx = i + (j < m ? j : m - 1);
            const int2 ed = sorted[idx];
            cc[j] = ed.x;
            vv[j] = (j < m) ? __int_as_float(ed.y) : 0.f;
        }
        unsigned p[8];
        #pragma unroll
        for (int j = 0; j < 8; ++j)
            p[j] = *(const unsigned*)(support + (size_t)cc[j] * D + lane * 2);
        #pragma unroll
        for (int j = 0; j < 8; ++j) {
            ax += __builtin_bit_cast(float, p[j] << 16) * vv[j];
            ay += __builtin_bit_cast(float, p[j] & 0xFFFF0000u) * vv[j];
        }
    }

    float* o = out + (size_t)row * D + lane * 2;
    float2 ov = *(const float2*)o;
    ov.x += ax;
    ov.y += ay;
    *(float2*)o = ov;
}

extern "C" void kernel_launch(void* const* d_in, const int* in_sizes, int n_in,
                              void* d_out, int out_size, void* d_ws, size_t ws_size,
                              hipStream_t stream) {
    const float* x     = (const float*)d_in[0];
    const int*   erows = (const int*)d_in[1];
    const int*   ecols = (const int*)d_in[2];
    const float* evals = (const float*)d_in[3];
    const float* W     = (const float*)d_in[4];
    const float* Wr    = (const float*)d_in[5];
    float* out = (float*)d_out;

    const int M = in_sizes[0] / D;   // 50000
    const int E = in_sizes[1];       // 800000

    unsigned short* support = (unsigned short*)d_ws;            // M*D bf16
    unsigned short* Wt      = support + (size_t)M * D;          // 2*D*D bf16
    int*   counts     = (int*)(Wt + 2 * D * D);                 // M
    int*   row_start  = counts + M;                             // M+2
    int*   cursor     = row_start + M + 2;                      // M
    int*   block_sums = cursor + M;                             // 64
    int2*  sorted     = (int2*)(block_sums + 64);               // E

    const int NB = (M + 1023) / 1024;           // 49
    const int eb = (E + 255) / 256;
    const int prep_grid = ((M > 2 * D * D ? M : 2 * D * D) + 255) / 256;
    const int rpp = (M + NPART - 1) / NPART;    // 6250 rows per partition

    prep<<<prep_grid, 256, 0, stream>>>(W, Wr, Wt, counts, M);
    gemm_dual_mfma<<<(M + 63) / 64, 256, 0, stream>>>(x, Wt, support, out, M);
    edge_histogram<<<eb, 256, 0, stream>>>(erows, counts, E);
    scan_local<<<NB, 256, 0, stream>>>(counts, row_start, block_sums, M);
    scan_blocks<<<1, 64, 0, stream>>>(block_sums, row_start, NB, M);
    add_offsets<<<NB, 256, 0, stream>>>(block_sums, row_start, cursor, M);
    part_scatter<<<NPART * SUBC, 256, 0, stream>>>(erows, ecols, evals, cursor, sorted, E, rpp);
    row_aggregate<<<(M + 3) / 4, 256, 0, stream>>>(row_start, sorted, support, out, M);
}

// Round 9
// 183.721 us; speedup vs baseline: 4.4861x; 1.2021x over previous
//
#include <hip/hip_runtime.h>

#define D 128
#define NC 128            // edge chunks
#define RPB 128           // rows per bucket
#define MAXBUCK 512

typedef short short8 __attribute__((ext_vector_type(8)));
typedef float v4f __attribute__((ext_vector_type(4)));

static __device__ __forceinline__ unsigned short f2bf(float f) {
    unsigned u = __builtin_bit_cast(unsigned, f);
    u = (u + 0x7FFFu + ((u >> 16) & 1u)) >> 16;   // RNE
    return (unsigned short)u;
}

// ---------------- prep: Wt[n][k] = (W||Wr)[k][n] as bf16 --------------------
__global__ __launch_bounds__(256) void prep(
    const float* __restrict__ W, const float* __restrict__ Wr,
    unsigned short* __restrict__ Wt)
{
    const int gid = blockIdx.x * 256 + threadIdx.x;
    if (gid < 2 * D * D) {
        const int k  = gid >> 8;
        const int nn = gid & 255;
        const float v = (nn < D) ? W[k * D + nn] : Wr[k * D + (nn - D)];
        Wt[nn * D + k] = f2bf(v);
    }
}

// ---------------- MFMA dual GEMM: support(bf16) = x@W, out(f32) = x@Wr ------
__global__ __launch_bounds__(256) void gemm_dual_mfma(
    const float* __restrict__ x, const unsigned short* __restrict__ Wt,
    unsigned short* __restrict__ support, float* __restrict__ out, int M)
{
    __shared__ unsigned short As[64][136];
    const int tid = threadIdx.x;
    const int w = tid >> 6;
    const int lane = tid & 63;
    const int nl = lane & 15, quad = lane >> 4;
    const int rowBase = blockIdx.x * 64;

    {
        const int r = tid & 63;
        const int seg = tid >> 6;
        const int row = rowBase + r;
        unsigned short tmp[32];
        if (row < M) {
            const float4* src = (const float4*)(x + (size_t)row * D + seg * 32);
            #pragma unroll
            for (int j = 0; j < 8; ++j) {
                const float4 v = src[j];
                tmp[j * 4 + 0] = f2bf(v.x); tmp[j * 4 + 1] = f2bf(v.y);
                tmp[j * 4 + 2] = f2bf(v.z); tmp[j * 4 + 3] = f2bf(v.w);
            }
        } else {
            #pragma unroll
            for (int j = 0; j < 32; ++j) tmp[j] = 0;
        }
        #pragma unroll
        for (int j = 0; j < 4; ++j)
            *(short8*)&As[r][seg * 32 + j * 8] = *(const short8*)&tmp[j * 8];
    }

    short8 bfrag[4][4];
    {
        const unsigned short* wbase = Wt + (size_t)(w * 64 + nl) * D + quad * 8;
        #pragma unroll
        for (int nt = 0; nt < 4; ++nt)
            #pragma unroll
            for (int c = 0; c < 4; ++c)
                bfrag[c][nt] = *(const short8*)(wbase + (size_t)nt * 16 * D + c * 32);
    }
    __syncthreads();

    v4f acc[4][4] = {};
    #pragma unroll
    for (int c = 0; c < 4; ++c) {
        short8 afr[4];
        #pragma unroll
        for (int mt = 0; mt < 4; ++mt)
            afr[mt] = *(const short8*)&As[mt * 16 + nl][c * 32 + quad * 8];
        #pragma unroll
        for (int mt = 0; mt < 4; ++mt)
            #pragma unroll
            for (int nt = 0; nt < 4; ++nt)
                acc[mt][nt] = __builtin_amdgcn_mfma_f32_16x16x32_bf16(
                    afr[mt], bfrag[c][nt], acc[mt][nt], 0, 0, 0);
    }

    const int cbase = (w & 1) * 64;
    if (w < 2) {
        #pragma unroll
        for (int mt = 0; mt < 4; ++mt)
            #pragma unroll
            for (int reg = 0; reg < 4; ++reg) {
                const int row = rowBase + mt * 16 + quad * 4 + reg;
                if (row < M) {
                    #pragma unroll
                    for (int nt = 0; nt < 4; ++nt)
                        support[(size_t)row * D + cbase + nt * 16 + nl] = f2bf(acc[mt][nt][reg]);
                }
            }
    } else {
        #pragma unroll
        for (int mt = 0; mt < 4; ++mt)
            #pragma unroll
            for (int reg = 0; reg < 4; ++reg) {
                const int row = rowBase + mt * 16 + quad * 4 + reg;
                if (row < M) {
                    #pragma unroll
                    for (int nt = 0; nt < 4; ++nt)
                        out[(size_t)row * D + cbase + nt * 16 + nl] = acc[mt][nt][reg];
                }
            }
    }
}

// ---------------- bucket histogram: countsT[b*NC + c] -----------------------
__global__ __launch_bounds__(256) void bucket_hist(
    const int* __restrict__ rows, int* __restrict__ countsT,
    int E, int nbuck, int chunk)
{
    __shared__ int hist[MAXBUCK];
    const int t = threadIdx.x, c = blockIdx.x;
    for (int i = t; i < nbuck; i += 256) hist[i] = 0;
    __syncthreads();
    const int base = c * chunk;
    const int endv = min(base + chunk, E);
    for (int e = base + t; e < endv; e += 256)
        atomicAdd(&hist[__builtin_nontemporal_load(rows + e) >> 7], 1);
    __syncthreads();
    for (int i = t; i < nbuck; i += 256) countsT[i * NC + c] = hist[i];
}

// ---------------- scan trio (n = nbuck*NC) ----------------------------------
__global__ __launch_bounds__(256) void scan_local(
    const int* __restrict__ counts, int* __restrict__ eoff,
    int* __restrict__ block_sums, int n)
{
    __shared__ int tmp[256];
    const int b = blockIdx.x, t = threadIdx.x;
    const int base = b * 1024 + t * 4;
    int v0 = 0, v1 = 0, v2 = 0, v3 = 0;
    if (base + 3 < n) {
        const int4 q = *(const int4*)(counts + base);
        v0 = q.x; v1 = q.y; v2 = q.z; v3 = q.w;
    } else {
        if (base + 0 < n) v0 = counts[base + 0];
        if (base + 1 < n) v1 = counts[base + 1];
        if (base + 2 < n) v2 = counts[base + 2];
    }
    const int s01 = v0 + v1;
    const int tsum = s01 + v2 + v3;
    tmp[t] = tsum;
    __syncthreads();
    for (int off = 1; off < 256; off <<= 1) {
        const int u = (t >= off) ? tmp[t - off] : 0;
        __syncthreads();
        tmp[t] += u;
        __syncthreads();
    }
    const int excl = tmp[t] - tsum;
    const int e0 = excl, e1 = excl + v0, e2 = excl + s01, e3 = e2 + v2;
    if (base + 3 < n) {
        *(int4*)(eoff + base) = make_int4(e0, e1, e2, e3);
    } else {
        if (base + 0 < n) eoff[base + 0] = e0;
        if (base + 1 < n) eoff[base + 1] = e1;
        if (base + 2 < n) eoff[base + 2] = e2;
    }
    if (t == 255) block_sums[b] = tmp[255];
}

__global__ __launch_bounds__(64) void scan_blocks(
    int* __restrict__ block_sums, int* __restrict__ eoff, int nb, int n)
{
    __shared__ int tmp[64];
    const int t = threadIdx.x;
    const int v = (t < nb) ? block_sums[t] : 0;
    tmp[t] = v;
    __syncthreads();
    for (int off = 1; off < 64; off <<= 1) {
        const int u = (t >= off) ? tmp[t - off] : 0;
        __syncthreads();
        tmp[t] += u;
        __syncthreads();
    }
    if (t < nb) block_sums[t] = tmp[t] - v;
    if (t == 63) eoff[n] = tmp[63];   // == E
}

__global__ __launch_bounds__(256) void add_offsets(
    const int* __restrict__ block_sums, int* __restrict__ eoff, int n)
{
    const int b = blockIdx.x;
    const int off = block_sums[b];
    const int base = b * 1024 + threadIdx.x * 4;
    if (base + 3 < n) {
        int4 q = *(const int4*)(eoff + base);
        q.x += off; q.y += off; q.z += off; q.w += off;
        *(int4*)(eoff + base) = q;
    } else {
        #pragma unroll
        for (int j = 0; j < 4; ++j) {
            const int i = base + j;
            if (i < n) eoff[i] += off;
        }
    }
}

// ---------------- bucketed scatter: contiguous runs per (bucket,chunk) ------
__global__ __launch_bounds__(256) void bucket_scatter(
    const int* __restrict__ rows, const int* __restrict__ cols,
    const float* __restrict__ vals, const int* __restrict__ eoff,
    int2* __restrict__ sortedB, int E, int nbuck, int chunk)
{
    __shared__ int cur[MAXBUCK];
    const int t = threadIdx.x, c = blockIdx.x;
    for (int i = t; i < nbuck; i += 256) cur[i] = eoff[i * NC + c];
    __syncthreads();
    const int base = c * chunk;
    const int endv = min(base + chunk, E);
    for (int e = base + t; e < endv; e += 256) {
        const int r  = __builtin_nontemporal_load(rows + e);
        const int cl = __builtin_nontemporal_load(cols + e);
        const float v = __builtin_nontemporal_load(vals + e);
        const int bk = r >> 7;
        const int pos = atomicAdd(&cur[bk], 1);
        sortedB[pos] = make_int2(((r & (RPB - 1)) << 16) | cl, __float_as_int(v));
    }
}

// ---------------- per-bucket LDS counting sort -> true CSR ------------------
// One block per bucket. The bucket's 16KB output window is written only by
// this block while L2-hot -> full-line writebacks.
__global__ __launch_bounds__(256) void bucket_sort(
    const int* __restrict__ eoff, const int2* __restrict__ sortedB,
    int2* __restrict__ sortedF, int* __restrict__ row_start, int nbuck)
{
    __shared__ int hist[RPB];
    __shared__ int scn[RPB];
    const int b = blockIdx.x, t = threadIdx.x;
    const int base = eoff[b * NC];
    const int endv = eoff[(b + 1) * NC];
    if (t < RPB) hist[t] = 0;
    __syncthreads();
    for (int i = base + t; i < endv; i += 256)
        atomicAdd(&hist[sortedB[i].x >> 16], 1);
    __syncthreads();
    if (t < RPB) scn[t] = hist[t];
    __syncthreads();
    for (int off = 1; off < RPB; off <<= 1) {
        const int u = (t < RPB && t >= off) ? scn[t - off] : 0;
        __syncthreads();
        if (t < RPB) scn[t] += u;
        __syncthreads();
    }
    if (t < RPB) {
        const int ex = base + scn[t] - hist[t];   // exclusive + bucket base
        row_start[b * RPB + t] = ex;
        hist[t] = ex;                              // reuse as cursor
    }
    __syncthreads();
    for (int i = base + t; i < endv; i += 256) {
        const int2 ed = sortedB[i];                // L2-hot re-read
        const int rib = ed.x >> 16;
        const int pos = atomicAdd(&hist[rib], 1);
        sortedF[pos] = make_int2(ed.x & 0xFFFF, ed.y);
    }
}

// ---------------- Aggregation: wave per row, batched independent gathers ----
__global__ __launch_bounds__(256) void row_aggregate(
    const int* __restrict__ row_start, const int2* __restrict__ sorted,
    const unsigned short* __restrict__ support, float* __restrict__ out, int N)
{
    const int row = blockIdx.x * 4 + (threadIdx.x >> 6);
    const int lane = threadIdx.x & 63;
    if (row >= N) return;
    const int s = row_start[row];
    const int e = row_start[row + 1];
    if (s == e) return;

    float ax = 0.f, ay = 0.f;
    int i = s;

    for (; i + 8 <= e; i += 8) {
        int4 q0 = *(const int4*)(sorted + i + 0);
        int4 q1 = *(const int4*)(sorted + i + 2);
        int4 q2 = *(const int4*)(sorted + i + 4);
        int4 q3 = *(const int4*)(sorted + i + 6);
        const int  c[8] = {q0.x, q0.z, q1.x, q1.z, q2.x, q2.z, q3.x, q3.z};
        const int  vv[8] = {q0.y, q0.w, q1.y, q1.w, q2.y, q2.w, q3.y, q3.w};
        unsigned p[8];
        #pragma unroll
        for (int j = 0; j < 8; ++j)
            p[j] = *(const unsigned*)(support + (size_t)c[j] * D + lane * 2);
        #pragma unroll
        for (int j = 0; j < 8; ++j) {
            const float v = __int_as_float(vv[j]);
            ax += __builtin_bit_cast(float, p[j] << 16) * v;
            ay += __builtin_bit_cast(float, p[j] & 0xFFFF0000u) * v;
        }
    }

    if (i < e) {
        const int m = e - i;   // 1..7
        int cc[8]; float vv[8];
        #pragma unroll
        for (int j = 0; j < 8; ++j) {
            const int idx = i + (j < m ? j : m - 1);
            const int2 ed = sorted[idx];
            cc[j] = ed.x;
            vv[j] = (j < m) ? __int_as_float(ed.y) : 0.f;
        }
        unsigned p[8];
        #pragma unroll
        for (int j = 0; j < 8; ++j)
            p[j] = *(const unsigned*)(support + (size_t)cc[j] * D + lane * 2);
        #pragma unroll
        for (int j = 0; j < 8; ++j) {
            ax += __builtin_bit_cast(float, p[j] << 16) * vv[j];
            ay += __builtin_bit_cast(float, p[j] & 0xFFFF0000u) * vv[j];
        }
    }

    float* o = out + (size_t)row * D + lane * 2;
    float2 ov = *(const float2*)o;
    ov.x += ax;
    ov.y += ay;
    *(float2*)o = ov;
}

extern "C" void kernel_launch(void* const* d_in, const int* in_sizes, int n_in,
                              void* d_out, int out_size, void* d_ws, size_t ws_size,
                              hipStream_t stream) {
    const float* x     = (const float*)d_in[0];
    const int*   erows = (const int*)d_in[1];
    const int*   ecols = (const int*)d_in[2];
    const float* evals = (const float*)d_in[3];
    const float* W     = (const float*)d_in[4];
    const float* Wr    = (const float*)d_in[5];
    float* out = (float*)d_out;

    const int M = in_sizes[0] / D;   // 50000
    const int E = in_sizes[1];       // 800000

    const int nbuck = (M + RPB - 1) / RPB;         // 391
    const int n = nbuck * NC;                      // 50048
    const int chunk = (E + NC - 1) / NC;           // 6250

    // ws layout (int2 regions 8B-aligned: prefix element counts are even)
    unsigned short* support = (unsigned short*)d_ws;            // M*D bf16
    unsigned short* Wt      = support + (size_t)M * D;          // 2*D*D bf16
    int*   countsT    = (int*)(Wt + 2 * D * D);                 // n
    int*   eoff       = countsT + n;                            // n+2
    int*   block_sums = eoff + n + 2;                           // 64
    int*   row_start  = block_sums + 64;                        // nbuck*RPB+2
    int2*  sortedB    = (int2*)(row_start + nbuck * RPB + 2);   // E
    int2*  sortedF    = sortedB + E;                            // E

    const int NB = (n + 1023) / 1024;              // 49

    prep<<<(2 * D * D + 255) / 256, 256, 0, stream>>>(W, Wr, Wt);
    gemm_dual_mfma<<<(M + 63) / 64, 256, 0, stream>>>(x, Wt, support, out, M);
    bucket_hist<<<NC, 256, 0, stream>>>(erows, countsT, E, nbuck, chunk);
    scan_local<<<NB, 256, 0, stream>>>(countsT, eoff, block_sums, n);
    scan_blocks<<<1, 64, 0, stream>>>(block_sums, eoff, NB, n);
    add_offsets<<<NB, 256, 0, stream>>>(block_sums, eoff, n);
    bucket_scatter<<<NC, 256, 0, stream>>>(erows, ecols, evals, eoff, sortedB, E, nbuck, chunk);
    bucket_sort<<<nbuck, 256, 0, stream>>>(eoff, sortedB, sortedF, row_start, nbuck);
    row_aggregate<<<(M + 3) / 4, 256, 0, stream>>>(row_start, sortedF, support, out, M);
}

// Round 10
// 183.183 us; speedup vs baseline: 4.4993x; 1.0029x over previous
//
#include <hip/hip_runtime.h>

#define D 128
#define NC 128            // edge chunks
#define RPB 128           // rows per bucket
#define MAXBUCK 512

typedef short short8 __attribute__((ext_vector_type(8)));
typedef float v4f __attribute__((ext_vector_type(4)));

static __device__ __forceinline__ unsigned short f2bf(float f) {
    unsigned u = __builtin_bit_cast(unsigned, f);
    u = (u + 0x7FFFu + ((u >> 16) & 1u)) >> 16;   // RNE
    return (unsigned short)u;
}

// ---- bucket histogram + Wt prep fused (both 128-block shaped) --------------
// Wt[n][k] = (W||Wr)[k][n] as bf16 ; countsT[b*NC + c] = edges of bucket b in chunk c
__global__ __launch_bounds__(256) void bucket_hist_prep(
    const int* __restrict__ rows, int* __restrict__ countsT,
    const float* __restrict__ W, const float* __restrict__ Wr,
    unsigned short* __restrict__ Wt, int E, int nbuck, int chunk)
{
    __shared__ int hist[MAXBUCK];
    const int t = threadIdx.x, c = blockIdx.x;
    // prep slice: 32768 elements over 128 blocks = 256/block = 1/thread
    {
        const int gid = c * 256 + t;
        const int k  = gid >> 8;
        const int nn = gid & 255;
        const float v = (nn < D) ? W[k * D + nn] : Wr[k * D + (nn - D)];
        Wt[nn * D + k] = f2bf(v);
    }
    for (int i = t; i < nbuck; i += 256) hist[i] = 0;
    __syncthreads();
    const int base = c * chunk;
    const int endv = min(base + chunk, E);
    for (int e = base + t; e < endv; e += 256)
        atomicAdd(&hist[__builtin_nontemporal_load(rows + e) >> 7], 1);
    __syncthreads();
    for (int i = t; i < nbuck; i += 256) countsT[i * NC + c] = hist[i];
}

// ---------------- MFMA dual GEMM: support(bf16) = x@W, out(f32) = x@Wr ------
__global__ __launch_bounds__(256) void gemm_dual_mfma(
    const float* __restrict__ x, const unsigned short* __restrict__ Wt,
    unsigned short* __restrict__ support, float* __restrict__ out, int M)
{
    __shared__ unsigned short As[64][136];
    const int tid = threadIdx.x;
    const int w = tid >> 6;
    const int lane = tid & 63;
    const int nl = lane & 15, quad = lane >> 4;
    const int rowBase = blockIdx.x * 64;

    {
        const int r = tid & 63;
        const int seg = tid >> 6;
        const int row = rowBase + r;
        unsigned short tmp[32];
        if (row < M) {
            const float4* src = (const float4*)(x + (size_t)row * D + seg * 32);
            #pragma unroll
            for (int j = 0; j < 8; ++j) {
                const float4 v = src[j];
                tmp[j * 4 + 0] = f2bf(v.x); tmp[j * 4 + 1] = f2bf(v.y);
                tmp[j * 4 + 2] = f2bf(v.z); tmp[j * 4 + 3] = f2bf(v.w);
            }
        } else {
            #pragma unroll
            for (int j = 0; j < 32; ++j) tmp[j] = 0;
        }
        #pragma unroll
        for (int j = 0; j < 4; ++j)
            *(short8*)&As[r][seg * 32 + j * 8] = *(const short8*)&tmp[j * 8];
    }

    short8 bfrag[4][4];
    {
        const unsigned short* wbase = Wt + (size_t)(w * 64 + nl) * D + quad * 8;
        #pragma unroll
        for (int nt = 0; nt < 4; ++nt)
            #pragma unroll
            for (int c = 0; c < 4; ++c)
                bfrag[c][nt] = *(const short8*)(wbase + (size_t)nt * 16 * D + c * 32);
    }
    __syncthreads();

    v4f acc[4][4] = {};
    #pragma unroll
    for (int c = 0; c < 4; ++c) {
        short8 afr[4];
        #pragma unroll
        for (int mt = 0; mt < 4; ++mt)
            afr[mt] = *(const short8*)&As[mt * 16 + nl][c * 32 + quad * 8];
        #pragma unroll
        for (int mt = 0; mt < 4; ++mt)
            #pragma unroll
            for (int nt = 0; nt < 4; ++nt)
                acc[mt][nt] = __builtin_amdgcn_mfma_f32_16x16x32_bf16(
                    afr[mt], bfrag[c][nt], acc[mt][nt], 0, 0, 0);
    }

    const int cbase = (w & 1) * 64;
    if (w < 2) {
        #pragma unroll
        for (int mt = 0; mt < 4; ++mt)
            #pragma unroll
            for (int reg = 0; reg < 4; ++reg) {
                const int row = rowBase + mt * 16 + quad * 4 + reg;
                if (row < M) {
                    #pragma unroll
                    for (int nt = 0; nt < 4; ++nt)
                        support[(size_t)row * D + cbase + nt * 16 + nl] = f2bf(acc[mt][nt][reg]);
                }
            }
    } else {
        #pragma unroll
        for (int mt = 0; mt < 4; ++mt)
            #pragma unroll
            for (int reg = 0; reg < 4; ++reg) {
                const int row = rowBase + mt * 16 + quad * 4 + reg;
                if (row < M) {
                    #pragma unroll
                    for (int nt = 0; nt < 4; ++nt)
                        out[(size_t)row * D + cbase + nt * 16 + nl] = acc[mt][nt][reg];
                }
            }
    }
}

// ---------------- scan: local pass + offsets pass (n = nbuck*NC) ------------
__global__ __launch_bounds__(256) void scan_local(
    const int* __restrict__ counts, int* __restrict__ eoff,
    int* __restrict__ block_sums, int n)
{
    __shared__ int tmp[256];
    const int b = blockIdx.x, t = threadIdx.x;
    const int base = b * 1024 + t * 4;
    int v0 = 0, v1 = 0, v2 = 0, v3 = 0;
    if (base + 3 < n) {
        const int4 q = *(const int4*)(counts + base);
        v0 = q.x; v1 = q.y; v2 = q.z; v3 = q.w;
    } else {
        if (base + 0 < n) v0 = counts[base + 0];
        if (base + 1 < n) v1 = counts[base + 1];
        if (base + 2 < n) v2 = counts[base + 2];
    }
    const int s01 = v0 + v1;
    const int tsum = s01 + v2 + v3;
    tmp[t] = tsum;
    __syncthreads();
    for (int off = 1; off < 256; off <<= 1) {
        const int u = (t >= off) ? tmp[t - off] : 0;
        __syncthreads();
        tmp[t] += u;
        __syncthreads();
    }
    const int excl = tmp[t] - tsum;
    const int e0 = excl, e1 = excl + v0, e2 = excl + s01, e3 = e2 + v2;
    if (base + 3 < n) {
        *(int4*)(eoff + base) = make_int4(e0, e1, e2, e3);
    } else {
        if (base + 0 < n) eoff[base + 0] = e0;
        if (base + 1 < n) eoff[base + 1] = e1;
        if (base + 2 < n) eoff[base + 2] = e2;
    }
    if (t == 255) block_sums[b] = tmp[255];
}

// add per-block offsets; each block derives its own prefix from block_sums.
__global__ __launch_bounds__(256) void add_offsets(
    const int* __restrict__ block_sums, int* __restrict__ eoff, int n, int nb)
{
    __shared__ int sb[64];
    const int b = blockIdx.x, t = threadIdx.x;
    if (t < 64) sb[t] = (t < nb) ? block_sums[t] : 0;
    __syncthreads();
    int off = 0, tot = 0;
    for (int i = 0; i < nb; ++i) {
        const int v = sb[i];
        if (i < b) off += v;
        tot += v;
    }
    const int base = b * 1024 + t * 4;
    if (base + 3 < n) {
        int4 q = *(const int4*)(eoff + base);
        q.x += off; q.y += off; q.z += off; q.w += off;
        *(int4*)(eoff + base) = q;
    } else {
        #pragma unroll
        for (int j = 0; j < 4; ++j) {
            const int i = base + j;
            if (i < n) eoff[i] += off;
        }
    }
    if (b == nb - 1 && t == 0) eoff[n] = tot;   // == E
}

// ---------------- bucketed scatter: contiguous runs per (bucket,chunk) ------
__global__ __launch_bounds__(256) void bucket_scatter(
    const int* __restrict__ rows, const int* __restrict__ cols,
    const float* __restrict__ vals, const int* __restrict__ eoff,
    int2* __restrict__ sortedB, int E, int nbuck, int chunk)
{
    __shared__ int cur[MAXBUCK];
    const int t = threadIdx.x, c = blockIdx.x;
    for (int i = t; i < nbuck; i += 256) cur[i] = eoff[i * NC + c];
    __syncthreads();
    const int base = c * chunk;
    const int endv = min(base + chunk, E);
    for (int e = base + t; e < endv; e += 256) {
        const int r  = __builtin_nontemporal_load(rows + e);
        const int cl = __builtin_nontemporal_load(cols + e);
        const float v = __builtin_nontemporal_load(vals + e);
        const int bk = r >> 7;
        const int pos = atomicAdd(&cur[bk], 1);
        sortedB[pos] = make_int2(((r & (RPB - 1)) << 16) | cl, __float_as_int(v));
    }
}

// ---------------- per-bucket LDS counting sort -> true CSR ------------------
__global__ __launch_bounds__(256) void bucket_sort(
    const int* __restrict__ eoff, const int2* __restrict__ sortedB,
    int2* __restrict__ sortedF, int* __restrict__ row_start, int nbuck)
{
    __shared__ int hist[RPB];
    __shared__ int scn[RPB];
    const int b = blockIdx.x, t = threadIdx.x;
    const int base = eoff[b * NC];
    const int endv = eoff[(b + 1) * NC];
    if (t < RPB) hist[t] = 0;
    __syncthreads();
    for (int i = base + t; i < endv; i += 256)
        atomicAdd(&hist[sortedB[i].x >> 16], 1);
    __syncthreads();
    if (t < RPB) scn[t] = hist[t];
    __syncthreads();
    for (int off = 1; off < RPB; off <<= 1) {
        const int u = (t < RPB && t >= off) ? scn[t - off] : 0;
        __syncthreads();
        if (t < RPB) scn[t] += u;
        __syncthreads();
    }
    if (t < RPB) {
        const int ex = base + scn[t] - hist[t];
        row_start[b * RPB + t] = ex;
        hist[t] = ex;                              // reuse as cursor
    }
    __syncthreads();
    for (int i = base + t; i < endv; i += 256) {
        const int2 ed = sortedB[i];
        const int rib = ed.x >> 16;
        const int pos = atomicAdd(&hist[rib], 1);
        sortedF[pos] = make_int2(ed.x & 0xFFFF, ed.y);
    }
}

// ---------------- Aggregation: wave per row, 16 gathers in flight -----------
__global__ __launch_bounds__(256) void row_aggregate(
    const int* __restrict__ row_start, const int2* __restrict__ sorted,
    const unsigned short* __restrict__ support, float* __restrict__ out, int N)
{
    const int row = blockIdx.x * 4 + (threadIdx.x >> 6);
    const int lane = threadIdx.x & 63;
    if (row >= N) return;
    const int s = row_start[row];
    const int e = row_start[row + 1];
    if (s == e) return;

    float ax = 0.f, ay = 0.f;
    int i = s;

    // batch-16: 8x int4 descriptor loads, then 16 independent gathers
    for (; i + 16 <= e; i += 16) {
        int4 q[8];
        #pragma unroll
        for (int j = 0; j < 8; ++j) q[j] = *(const int4*)(sorted + i + 2 * j);
        int c[16], vv[16];
        #pragma unroll
        for (int j = 0; j < 8; ++j) {
            c[2 * j]     = q[j].x; vv[2 * j]     = q[j].y;
            c[2 * j + 1] = q[j].z; vv[2 * j + 1] = q[j].w;
        }
        unsigned p[16];
        #pragma unroll
        for (int j = 0; j < 16; ++j)
            p[j] = *(const unsigned*)(support + (size_t)c[j] * D + lane * 2);
        #pragma unroll
        for (int j = 0; j < 16; ++j) {
            const float v = __int_as_float(vv[j]);
            ax += __builtin_bit_cast(float, p[j] << 16) * v;
            ay += __builtin_bit_cast(float, p[j] & 0xFFFF0000u) * v;
        }
    }

    if (i + 8 <= e) {
        const int4 q0 = *(const int4*)(sorted + i + 0);
        const int4 q1 = *(const int4*)(sorted + i + 2);
        const int4 q2 = *(const int4*)(sorted + i + 4);
        const int4 q3 = *(const int4*)(sorted + i + 6);
        const int  c[8] = {q0.x, q0.z, q1.x, q1.z, q2.x, q2.z, q3.x, q3.z};
        const int  vv[8] = {q0.y, q0.w, q1.y, q1.w, q2.y, q2.w, q3.y, q3.w};
        unsigned p[8];
        #pragma unroll
        for (int j = 0; j < 8; ++j)
            p[j] = *(const unsigned*)(support + (size_t)c[j] * D + lane * 2);
        #pragma unroll
        for (int j = 0; j < 8; ++j) {
            const float v = __int_as_float(vv[j]);
            ax += __builtin_bit_cast(float, p[j] << 16) * v;
            ay += __builtin_bit_cast(float, p[j] & 0xFFFF0000u) * v;
        }
        i += 8;
    }

    if (i < e) {
        const int m = e - i;   // 1..7
        int cc[8]; float vv[8];
        #pragma unroll
        for (int j = 0; j < 8; ++j) {
            const int idx = i + (j < m ? j : m - 1);
            const int2 ed = sorted[idx];
            cc[j] = ed.x;
            vv[j] = (j < m) ? __int_as_float(ed.y) : 0.f;
        }
        unsigned p[8];
        #pragma unroll
        for (int j = 0; j < 8; ++j)
            p[j] = *(const unsigned*)(support + (size_t)cc[j] * D + lane * 2);
        #pragma unroll
        for (int j = 0; j < 8; ++j) {
            ax += __builtin_bit_cast(float, p[j] << 16) * vv[j];
            ay += __builtin_bit_cast(float, p[j] & 0xFFFF0000u) * vv[j];
        }
    }

    float* o = out + (size_t)row * D + lane * 2;
    float2 ov = *(const float2*)o;
    ov.x += ax;
    ov.y += ay;
    *(float2*)o = ov;
}

extern "C" void kernel_launch(void* const* d_in, const int* in_sizes, int n_in,
                              void* d_out, int out_size, void* d_ws, size_t ws_size,
                              hipStream_t stream) {
    const float* x     = (const float*)d_in[0];
    const int*   erows = (const int*)d_in[1];
    const int*   ecols = (const int*)d_in[2];
    const float* evals = (const float*)d_in[3];
    const float* W     = (const float*)d_in[4];
    const float* Wr    = (const float*)d_in[5];
    float* out = (float*)d_out;

    const int M = in_sizes[0] / D;   // 50000
    const int E = in_sizes[1];       // 800000

    const int nbuck = (M + RPB - 1) / RPB;         // 391
    const int n = nbuck * NC;                      // 50048
    const int chunk = (E + NC - 1) / NC;           // 6250

    // ws layout
    unsigned short* support = (unsigned short*)d_ws;            // M*D bf16
    unsigned short* Wt      = support + (size_t)M * D;          // 2*D*D bf16
    int*   countsT    = (int*)(Wt + 2 * D * D);                 // n
    int*   eoff       = countsT + n;                            // n+2
    int*   block_sums = eoff + n + 2;                           // 64
    int*   row_start  = block_sums + 64;                        // nbuck*RPB+2
    int2*  sortedB    = (int2*)(row_start + nbuck * RPB + 2);   // E
    int2*  sortedF    = sortedB + E;                            // E

    const int NB = (n + 1023) / 1024;              // 49

    bucket_hist_prep<<<NC, 256, 0, stream>>>(erows, countsT, W, Wr, Wt, E, nbuck, chunk);
    gemm_dual_mfma<<<(M + 63) / 64, 256, 0, stream>>>(x, Wt, support, out, M);
    scan_local<<<NB, 256, 0, stream>>>(countsT, eoff, block_sums, n);
    add_offsets<<<NB, 256, 0, stream>>>(block_sums, eoff, n, NB);
    bucket_scatter<<<NC, 256, 0, stream>>>(erows, ecols, evals, eoff, sortedB, E, nbuck, chunk);
    bucket_sort<<<nbuck, 256, 0, stream>>>(eoff, sortedB, sortedF, row_start, nbuck);
    row_aggregate<<<(M + 3) / 4, 256, 0, stream>>>(row_start, sortedF, support, out, M);
}

// Round 12
// 167.510 us; speedup vs baseline: 4.9202x; 1.0936x over previous
//
#include <hip/hip_runtime.h>

#define D 128
#define NC 256            // edge chunks
#define RPB 128           // rows per bucket
#define MAXBUCK 512

typedef short short8 __attribute__((ext_vector_type(8)));
typedef float v4f __attribute__((ext_vector_type(4)));
typedef unsigned uint4v __attribute__((ext_vector_type(4)));
typedef float float2v __attribute__((ext_vector_type(2)));

static __device__ __forceinline__ unsigned short f2bf(float f) {
    unsigned u = __builtin_bit_cast(unsigned, f);
    u = (u + 0x7FFFu + ((u >> 16) & 1u)) >> 16;   // RNE
    return (unsigned short)u;
}

// ---- bucket histogram + Wt prep fused --------------------------------------
// Wt[n][k] = (W||Wr)[k][n] bf16 ; countsT[b*NC + c] = edges of bucket b in chunk c
__global__ __launch_bounds__(256) void bucket_hist_prep(
    const int* __restrict__ rows, int* __restrict__ countsT,
    const float* __restrict__ W, const float* __restrict__ Wr,
    unsigned short* __restrict__ Wt, int E, int nbuck, int chunk)
{
    __shared__ int hist[MAXBUCK];
    const int t = threadIdx.x, c = blockIdx.x;
    // prep slice: 32768 elements over 256 blocks = 128/block
    if (t < 128) {
        const int gid = c * 128 + t;
        const int k  = gid >> 8;
        const int nn = gid & 255;
        const float v = (nn < D) ? W[k * D + nn] : Wr[k * D + (nn - D)];
        Wt[nn * D + k] = f2bf(v);
    }
    for (int i = t; i < nbuck; i += 256) hist[i] = 0;
    __syncthreads();
    const int base = c * chunk;
    const int endv = min(base + chunk, E);
    for (int e = base + t; e < endv; e += 256)
        atomicAdd(&hist[__builtin_nontemporal_load(rows + e) >> 7], 1);
    __syncthreads();
    for (int i = t; i < nbuck; i += 256) countsT[i * NC + c] = hist[i];
}

// ---------------- MFMA dual GEMM: support(bf16)=x@W, rootbuf(bf16)=x@Wr -----
__global__ __launch_bounds__(256) void gemm_dual_mfma(
    const float* __restrict__ x, const unsigned short* __restrict__ Wt,
    unsigned short* __restrict__ support, unsigned short* __restrict__ rootbuf,
    int M)
{
    __shared__ unsigned short As[64][136];
    const int tid = threadIdx.x;
    const int w = tid >> 6;
    const int lane = tid & 63;
    const int nl = lane & 15, quad = lane >> 4;
    const int rowBase = blockIdx.x * 64;

    {
        const int r = tid & 63;
        const int seg = tid >> 6;
        const int row = rowBase + r;
        unsigned short tmp[32];
        if (row < M) {
            const float4* src = (const float4*)(x + (size_t)row * D + seg * 32);
            #pragma unroll
            for (int j = 0; j < 8; ++j) {
                const float4 v = src[j];
                tmp[j * 4 + 0] = f2bf(v.x); tmp[j * 4 + 1] = f2bf(v.y);
                tmp[j * 4 + 2] = f2bf(v.z); tmp[j * 4 + 3] = f2bf(v.w);
            }
        } else {
            #pragma unroll
            for (int j = 0; j < 32; ++j) tmp[j] = 0;
        }
        #pragma unroll
        for (int j = 0; j < 4; ++j)
            *(short8*)&As[r][seg * 32 + j * 8] = *(const short8*)&tmp[j * 8];
    }

    short8 bfrag[4][4];
    {
        const unsigned short* wbase = Wt + (size_t)(w * 64 + nl) * D + quad * 8;
        #pragma unroll
        for (int nt = 0; nt < 4; ++nt)
            #pragma unroll
            for (int c = 0; c < 4; ++c)
                bfrag[c][nt] = *(const short8*)(wbase + (size_t)nt * 16 * D + c * 32);
    }
    __syncthreads();

    v4f acc[4][4] = {};
    #pragma unroll
    for (int c = 0; c < 4; ++c) {
        short8 afr[4];
        #pragma unroll
        for (int mt = 0; mt < 4; ++mt)
            afr[mt] = *(const short8*)&As[mt * 16 + nl][c * 32 + quad * 8];
        #pragma unroll
        for (int mt = 0; mt < 4; ++mt)
            #pragma unroll
            for (int nt = 0; nt < 4; ++nt)
                acc[mt][nt] = __builtin_amdgcn_mfma_f32_16x16x32_bf16(
                    afr[mt], bfrag[c][nt], acc[mt][nt], 0, 0, 0);
    }

    const int cbase = (w & 1) * 64;
    unsigned short* dst = (w < 2) ? support : rootbuf;
    #pragma unroll
    for (int mt = 0; mt < 4; ++mt)
        #pragma unroll
        for (int reg = 0; reg < 4; ++reg) {
            const int row = rowBase + mt * 16 + quad * 4 + reg;
            if (row < M) {
                #pragma unroll
                for (int nt = 0; nt < 4; ++nt)
                    dst[(size_t)row * D + cbase + nt * 16 + nl] = f2bf(acc[mt][nt][reg]);
            }
        }
}

// ---------------- scan: local pass + offsets pass (n = nbuck*NC) ------------
__global__ __launch_bounds__(256) void scan_local(
    const int* __restrict__ counts, int* __restrict__ eoff,
    int* __restrict__ block_sums, int n)
{
    __shared__ int tmp[256];
    const int b = blockIdx.x, t = threadIdx.x;
    const int base = b * 1024 + t * 4;
    int v0 = 0, v1 = 0, v2 = 0, v3 = 0;
    if (base + 3 < n) {
        const int4 q = *(const int4*)(counts + base);
        v0 = q.x; v1 = q.y; v2 = q.z; v3 = q.w;
    } else {
        if (base + 0 < n) v0 = counts[base + 0];
        if (base + 1 < n) v1 = counts[base + 1];
        if (base + 2 < n) v2 = counts[base + 2];
    }
    const int s01 = v0 + v1;
    const int tsum = s01 + v2 + v3;
    tmp[t] = tsum;
    __syncthreads();
    for (int off = 1; off < 256; off <<= 1) {
        const int u = (t >= off) ? tmp[t - off] : 0;
        __syncthreads();
        tmp[t] += u;
        __syncthreads();
    }
    const int excl = tmp[t] - tsum;
    const int e0 = excl, e1 = excl + v0, e2 = excl + s01, e3 = e2 + v2;
    if (base + 3 < n) {
        *(int4*)(eoff + base) = make_int4(e0, e1, e2, e3);
    } else {
        if (base + 0 < n) eoff[base + 0] = e0;
        if (base + 1 < n) eoff[base + 1] = e1;
        if (base + 2 < n) eoff[base + 2] = e2;
    }
    if (t == 255) block_sums[b] = tmp[255];
}

__global__ __launch_bounds__(256) void add_offsets(
    const int* __restrict__ block_sums, int* __restrict__ eoff, int n, int nb)
{
    __shared__ int sb[128];
    const int b = blockIdx.x, t = threadIdx.x;
    if (t < 128) sb[t] = (t < nb) ? block_sums[t] : 0;
    __syncthreads();
    int off = 0, tot = 0;
    for (int i = 0; i < nb; ++i) {
        const int v = sb[i];
        if (i < b) off += v;
        tot += v;
    }
    const int base = b * 1024 + t * 4;
    if (base + 3 < n) {
        int4 q = *(const int4*)(eoff + base);
        q.x += off; q.y += off; q.z += off; q.w += off;
        *(int4*)(eoff + base) = q;
    } else {
        #pragma unroll
        for (int j = 0; j < 4; ++j) {
            const int i = base + j;
            if (i < n) eoff[i] += off;
        }
    }
    if (b == nb - 1 && t == 0) eoff[n] = tot;   // == E
}

// ---------------- bucketed scatter: contiguous runs per (bucket,chunk) ------
__global__ __launch_bounds__(256) void bucket_scatter(
    const int* __restrict__ rows, const int* __restrict__ cols,
    const float* __restrict__ vals, const int* __restrict__ eoff,
    int2* __restrict__ sortedB, int E, int nbuck, int chunk)
{
    __shared__ int cur[MAXBUCK];
    const int t = threadIdx.x, c = blockIdx.x;
    for (int i = t; i < nbuck; i += 256) cur[i] = eoff[i * NC + c];
    __syncthreads();
    const int base = c * chunk;
    const int endv = min(base + chunk, E);
    for (int e = base + t; e < endv; e += 256) {
        const int r  = __builtin_nontemporal_load(rows + e);
        const int cl = __builtin_nontemporal_load(cols + e);
        const float v = __builtin_nontemporal_load(vals + e);
        const int bk = r >> 7;
        const int pos = atomicAdd(&cur[bk], 1);
        sortedB[pos] = make_int2(((r & (RPB - 1)) << 16) | cl, __float_as_int(v));
    }
}

// ---------------- per-bucket LDS counting sort -> true CSR ------------------
// sortedF entry: (val_bf16 << 16) | col   -> val recovered by masking (free)
__global__ __launch_bounds__(256) void bucket_sort(
    const int* __restrict__ eoff, const int2* __restrict__ sortedB,
    unsigned* __restrict__ sortedF, int* __restrict__ row_start, int nbuck)
{
    __shared__ int hist[RPB];
    __shared__ int scn[RPB];
    const int b = blockIdx.x, t = threadIdx.x;
    const int base = eoff[b * NC];
    const int endv = eoff[(b + 1) * NC];
    if (t < RPB) hist[t] = 0;
    __syncthreads();
    for (int i = base + t; i < endv; i += 256)
        atomicAdd(&hist[sortedB[i].x >> 16], 1);
    __syncthreads();
    if (t < RPB) scn[t] = hist[t];
    __syncthreads();
    for (int off = 1; off < RPB; off <<= 1) {
        const int u = (t < RPB && t >= off) ? scn[t - off] : 0;
        __syncthreads();
        if (t < RPB) scn[t] += u;
        __syncthreads();
    }
    if (t < RPB) {
        const int ex = base + scn[t] - hist[t];
        row_start[b * RPB + t] = ex;
        hist[t] = ex;                              // reuse as cursor
    }
    __syncthreads();
    for (int i = base + t; i < endv; i += 256) {
        const int2 ed = sortedB[i];
        const int rib = ed.x >> 16;
        const int pos = atomicAdd(&hist[rib], 1);
        const unsigned vb = f2bf(__int_as_float(ed.y));
        sortedF[pos] = (vb << 16) | (unsigned)(ed.x & 0xFFFF);
    }
}

// ---------------- Aggregation: wave per row; out = agg + root (one write) ---
__global__ __launch_bounds__(256) void row_aggregate(
    const int* __restrict__ row_start, const unsigned* __restrict__ sorted,
    const unsigned short* __restrict__ support,
    const unsigned short* __restrict__ rootbuf,
    float* __restrict__ out, int N)
{
    const int row = blockIdx.x * 4 + (threadIdx.x >> 6);
    const int lane = threadIdx.x & 63;
    if (row >= N) return;
    const int s = row_start[row];
    const int e = row_start[row + 1];

    float ax = 0.f, ay = 0.f;
    int i = s;

    // batch-16: 4x uint4 NT descriptor loads, then 16 independent gathers
    for (; i + 16 <= e; i += 16) {
        uint4v q[4];
        #pragma unroll
        for (int j = 0; j < 4; ++j)
            q[j] = __builtin_nontemporal_load((const uint4v*)(sorted + i) + j);
        unsigned d[16];
        #pragma unroll
        for (int j = 0; j < 4; ++j) {
            d[4 * j] = q[j].x; d[4 * j + 1] = q[j].y;
            d[4 * j + 2] = q[j].z; d[4 * j + 3] = q[j].w;
        }
        unsigned p[16];
        #pragma unroll
        for (int j = 0; j < 16; ++j)
            p[j] = *(const unsigned*)(support + (size_t)(d[j] & 0xFFFF) * D + lane * 2);
        #pragma unroll
        for (int j = 0; j < 16; ++j) {
            const float v = __builtin_bit_cast(float, d[j] & 0xFFFF0000u);
            ax += __builtin_bit_cast(float, p[j] << 16) * v;
            ay += __builtin_bit_cast(float, p[j] & 0xFFFF0000u) * v;
        }
    }

    if (i + 8 <= e) {
        const uint4v q0 = __builtin_nontemporal_load((const uint4v*)(sorted + i));
        const uint4v q1 = __builtin_nontemporal_load((const uint4v*)(sorted + i) + 1);
        const unsigned d[8] = {q0.x, q0.y, q0.z, q0.w, q1.x, q1.y, q1.z, q1.w};
        unsigned p[8];
        #pragma unroll
        for (int j = 0; j < 8; ++j)
            p[j] = *(const unsigned*)(support + (size_t)(d[j] & 0xFFFF) * D + lane * 2);
        #pragma unroll
        for (int j = 0; j < 8; ++j) {
            const float v = __builtin_bit_cast(float, d[j] & 0xFFFF0000u);
            ax += __builtin_bit_cast(float, p[j] << 16) * v;
            ay += __builtin_bit_cast(float, p[j] & 0xFFFF0000u) * v;
        }
        i += 8;
    }

    if (i < e) {
        const int m = e - i;   // 1..7
        unsigned d[8];
        #pragma unroll
        for (int j = 0; j < 8; ++j) {
            const int idx = i + (j < m ? j : m - 1);
            const unsigned q = sorted[idx];
            d[j] = (j < m) ? q : (q & 0xFFFFu);    // zero val for pads
        }
        unsigned p[8];
        #pragma unroll
        for (int j = 0; j < 8; ++j)
            p[j] = *(const unsigned*)(support + (size_t)(d[j] & 0xFFFF) * D + lane * 2);
        #pragma unroll
        for (int j = 0; j < 8; ++j) {
            const float v = __builtin_bit_cast(float, d[j] & 0xFFFF0000u);
            ax += __builtin_bit_cast(float, p[j] << 16) * v;
            ay += __builtin_bit_cast(float, p[j] & 0xFFFF0000u) * v;
        }
    }

    // root term (bf16) + single NT store of out
    const unsigned pr = *(const unsigned*)(rootbuf + (size_t)row * D + lane * 2);
    float2v ov;
    ov.x = ax + __builtin_bit_cast(float, pr << 16);
    ov.y = ay + __builtin_bit_cast(float, pr & 0xFFFF0000u);
    __builtin_nontemporal_store(ov, (float2v*)(out + (size_t)row * D + lane * 2));
}

extern "C" void kernel_launch(void* const* d_in, const int* in_sizes, int n_in,
                              void* d_out, int out_size, void* d_ws, size_t ws_size,
                              hipStream_t stream) {
    const float* x     = (const float*)d_in[0];
    const int*   erows = (const int*)d_in[1];
    const int*   ecols = (const int*)d_in[2];
    const float* evals = (const float*)d_in[3];
    const float* W     = (const float*)d_in[4];
    const float* Wr    = (const float*)d_in[5];
    float* out = (float*)d_out;

    const int M = in_sizes[0] / D;   // 50000
    const int E = in_sizes[1];       // 800000

    const int nbuck = (M + RPB - 1) / RPB;         // 391
    const int n = nbuck * NC;                      // 100096
    const int chunk = (E + NC - 1) / NC;           // 3125

    // ws layout
    unsigned short* support = (unsigned short*)d_ws;            // M*D bf16
    unsigned short* Wt      = support + (size_t)M * D;          // 2*D*D bf16
    unsigned short* rootbuf = Wt + 2 * D * D;                   // M*D bf16
    int*      countsT    = (int*)(rootbuf + (size_t)M * D);     // n
    int*      eoff       = countsT + n;                         // n+2
    int*      block_sums = eoff + n + 2;                        // 128
    int*      row_start  = block_sums + 128;                    // nbuck*RPB+2
    int2*     sortedB    = (int2*)(row_start + nbuck * RPB + 2);// E
    unsigned* sortedF    = (unsigned*)(sortedB + E);            // E

    const int NB = (n + 1023) / 1024;              // 98

    bucket_hist_prep<<<NC, 256, 0, stream>>>(erows, countsT, W, Wr, Wt, E, nbuck, chunk);
    gemm_dual_mfma<<<(M + 63) / 64, 256, 0, stream>>>(x, Wt, support, rootbuf, M);
    scan_local<<<NB, 256, 0, stream>>>(countsT, eoff, block_sums, n);
    add_offsets<<<NB, 256, 0, stream>>>(block_sums, eoff, n, NB);
    bucket_scatter<<<NC, 256, 0, stream>>>(erows, ecols, evals, eoff, sortedB, E, nbuck, chunk);
    bucket_sort<<<nbuck, 256, 0, stream>>>(eoff, sortedB, sortedF, row_start, nbuck);
    row_aggregate<<<(M + 3) / 4, 256, 0, stream>>>(row_start, sortedF, support, rootbuf, out, M);
}